// Round 11
// baseline (6398.603 us; speedup 1.0000x reference)
//
#include <hip/hip_runtime.h>
#include <math.h>

#define BATCH 32
#define TLEN  512
#define HID   1024
#define G2    2048   // 2*H
#define BHID (BATCH * HID)

typedef _Float16 half8 __attribute__((ext_vector_type(8)));
typedef float f32x4 __attribute__((ext_vector_type(4)));

// ---------------------------------------------------------------------------
// fp32 -> fp16 conversion (8 elems/thread)
// ---------------------------------------------------------------------------
__global__ __launch_bounds__(256)
void conv_f16(const float* __restrict__ s, _Float16* __restrict__ d, int n8) {
    int i = blockIdx.x * 256 + threadIdx.x;
    if (i < n8) {
        int base = i * 8;
        float4 v0 = *(const float4*)&s[base];
        float4 v1 = *(const float4*)&s[base + 4];
        half8 h;
        h[0] = (_Float16)v0.x; h[1] = (_Float16)v0.y;
        h[2] = (_Float16)v0.z; h[3] = (_Float16)v0.w;
        h[4] = (_Float16)v1.x; h[5] = (_Float16)v1.y;
        h[6] = (_Float16)v1.z; h[7] = (_Float16)v1.w;
        *(half8*)&d[base] = h;
    }
}

// ---------------------------------------------------------------------------
// MFMA projection GEMM: Cw[t][b][n] = sum_k A[m][k] * W[n][k], m = b*T + t.
// A [M,K] fp16 row-major, W [N=2048,K] fp16 row-major. No LDS: A/B frags
// loaded straight from global (L2/LLC-resident), 16B contiguous per lane.
// WG 256 thr = 4 waves (2x2), wave tile 64x64 = 4x4 mfma_16x16x32 frags.
// ---------------------------------------------------------------------------
__global__ __launch_bounds__(256)
void proj_gemm_f16(const _Float16* __restrict__ A, const _Float16* __restrict__ W,
                   float* __restrict__ Cw, int K) {
    const int tid = threadIdx.x;
    const int wv = tid >> 6;
    const int l  = tid & 63;
    const int m0 = blockIdx.x * 128 + (wv >> 1) * 64;
    const int n0 = blockIdx.y * 128 + (wv & 1) * 64;
    const int fr = l & 15;            // A/B frag row (M or N)
    const int kg = l >> 4;            // k-group (8 halves each)

    f32x4 acc[4][4];
    #pragma unroll
    for (int i = 0; i < 4; ++i)
        #pragma unroll
        for (int j = 0; j < 4; ++j) acc[i][j] = (f32x4){0.f, 0.f, 0.f, 0.f};

    const int nkc = K >> 5;
    #pragma unroll 2
    for (int kc = 0; kc < nkc; ++kc) {
        int k = kc * 32 + kg * 8;
        half8 af[4], bf[4];
        #pragma unroll
        for (int i = 0; i < 4; ++i)
            af[i] = *(const half8*)&A[(size_t)(m0 + i * 16 + fr) * K + k];
        #pragma unroll
        for (int j = 0; j < 4; ++j)
            bf[j] = *(const half8*)&W[(size_t)(n0 + j * 16 + fr) * K + k];
        #pragma unroll
        for (int i = 0; i < 4; ++i)
            #pragma unroll
            for (int j = 0; j < 4; ++j)
                acc[i][j] = __builtin_amdgcn_mfma_f32_16x16x32_f16(
                    af[i], bf[j], acc[i][j], 0, 0, 0);
    }

    // C layout: col = l&15, row = (l>>4)*4 + r (verified R10)
    #pragma unroll
    for (int i = 0; i < 4; ++i) {
        #pragma unroll
        for (int r = 0; r < 4; ++r) {
            int m = m0 + i * 16 + (l >> 4) * 4 + r;
            int t = m & (TLEN - 1);
            int b = m >> 9;
            float* dst = &Cw[((size_t)t * BATCH + b) * G2];
            #pragma unroll
            for (int j = 0; j < 4; ++j)
                dst[n0 + j * 16 + (l & 15)] = acc[i][j][r];
        }
    }
}

// ---------------------------------------------------------------------------
// Agent-scope (device-coherent) helpers: sc0 sc1, bypass L1/per-XCD L2.
// ---------------------------------------------------------------------------
__device__ __forceinline__ void st_flag(int* p, int v) {
    __hip_atomic_store(p, v, __ATOMIC_RELAXED, __HIP_MEMORY_SCOPE_AGENT);
}
__device__ __forceinline__ int ld_flag(const int* p) {
    return __hip_atomic_load(p, __ATOMIC_RELAXED, __HIP_MEMORY_SCOPE_AGENT);
}
__device__ __forceinline__ unsigned long long ld_h2u(const unsigned short* p) {
    return __hip_atomic_load((const unsigned long long*)p, __ATOMIC_RELAXED,
                             __HIP_MEMORY_SCOPE_AGENT);
}
__device__ __forceinline__ void st_h64(unsigned long long* p, unsigned long long v) {
    __hip_atomic_store(p, v, __ATOMIC_RELAXED, __HIP_MEMORY_SCOPE_AGENT);
}

#define NWG 256
#define FSTRIDE 16   // flags 64 B apart

__global__ void rec_init(unsigned short* h0, int* flags) {
    int i = blockIdx.x * 256 + threadIdx.x;
    if (i < BHID) h0[i] = 0;              // fp16 +0.0
    if (i < NWG * FSTRIDE) flags[i] = 0;
}

// ---------------------------------------------------------------------------
// MFMA recurrence, short-critical-path version.
// WG = 128 thr (2 waves). wg: bt = wg&1 (2 sync groups x 16 batches),
// jt = wg>>1 (0..127), j0 = jt*8. WG owns 8 j x 16 batches.
// Packed M-tile: A rows 0-7 = U_a[j0..j0+7], rows 8-15 = U_z[j0..j0+7]
// -> ONE mfma tile yields both gates; shfl_xor(32) pairs a_jb with z_jb
// in-register (C row=(l>>4)*4+r, lane bit5 <-> row bit3).
// Wave wv owns K-half wv*512..+512: 16 A-frags (64 VGPR, converted once).
// B frags: coherent 8B loads straight from fp16 h-ring (col = batch = l&15,
// 16 REAL batches -- no column duplication).
// Per step: [w prefetch] -> poll 128 group flags (2/lane, per-wave, no
// barrier) -> 16 chained MFMAs -> wave1 LDS-bounce (1KB) -> ONE syncthreads
// -> wave0: add, shfl, gates, h/out stores, s_waitcnt vmcnt(0), flag store.
// h ring 3-deep (WAR-free single-hop publish, proven R6).
// Layer 0 writes fp16 act (feeds layer-1 GEMM); layer 1 writes fp32 out.
// ---------------------------------------------------------------------------
__global__ __launch_bounds__(128, 1)
void ligru_rec(const float* __restrict__ w,        // [T][B][2H] fp32
               const float* __restrict__ U,        // [2H][H] fp32
               unsigned short* __restrict__ hring, // [3][B][H] fp16 ring
               int* __restrict__ flags,            // NWG*FSTRIDE, pre-zeroed
               float* __restrict__ out32,          // [B][T][H] fp32 (layer 1)
               _Float16* __restrict__ act16,       // [B][T][H] fp16 (layer 0)
               float* __restrict__ hlast) {        // [B][H] fp32
    __shared__ f32x4 red[2][64];                   // wave-1 partials (2KB)

    const int wg  = blockIdx.x;
    const int tid = threadIdx.x;
    const int bt  = wg & 1;
    const int jt  = wg >> 1;          // 0..127
    const int j0  = jt * 8;
    const int bg0 = bt * 16;

    const int wv  = tid >> 6;         // K-half
    const int l   = tid & 63;
    const int r16 = l & 15;           // A row / B col within tile
    const int kg  = l >> 4;

    // ---- A frags: packed a/z tile, fp32->fp16 once (16 frags = 64 VGPR)
    const int urow = (r16 < 8) ? (j0 + r16) : (HID + j0 + (r16 - 8));
    half8 Af[16];
    #pragma unroll
    for (int kc = 0; kc < 16; ++kc) {
        int k0 = wv * 512 + kc * 32 + kg * 8;
        const float* up = &U[(size_t)urow * HID + k0];
        float4 u0 = *(const float4*)up, u1 = *(const float4*)(up + 4);
        half8 v;
        v[0] = (_Float16)u0.x; v[1] = (_Float16)u0.y;
        v[2] = (_Float16)u0.z; v[3] = (_Float16)u0.w;
        v[4] = (_Float16)u1.x; v[5] = (_Float16)u1.y;
        v[6] = (_Float16)u1.z; v[7] = (_Float16)u1.w;
        Af[kc] = v;
    }

    unsigned short* h_t = hring;
    unsigned short* h_n = hring + BHID;
    unsigned short* h_p = hring + 2 * BHID;

    const int gate_lane = (wv == 0) && (l < 32);
    const int bcol = bg0 + (l & 15);              // batch column
    const int jrow = j0 + (l >> 4) * 4;           // first of 4 j's (gate lanes)
    f32x4 hprev = {0.f, 0.f, 0.f, 0.f};

    for (int t = 0; t < TLEN; ++t) {
        // ---- w prefetch (independent of flags; hides under poll)
        f32x4 wa4 = {0.f, 0.f, 0.f, 0.f}, wz4 = {0.f, 0.f, 0.f, 0.f};
        if (gate_lane) {
            const float* wt = &w[((size_t)t * BATCH + bcol) * G2];
            wa4 = *(const f32x4*)&wt[jrow];
            wz4 = *(const f32x4*)&wt[HID + jrow];
        }

        // ---- poll group flags (128 of them, 2 per lane; per-wave, no barrier)
        if (t > 0) {
            const int* f0 = &flags[(l * 2 + bt) * FSTRIDE];
            const int* f1 = &flags[((l + 64) * 2 + bt) * FSTRIDE];
            while (ld_flag(f0) < t || ld_flag(f1) < t)
                __builtin_amdgcn_s_sleep(1);
        }

        // ---- B frags from coherent ring + 16 chained MFMAs
        f32x4 c = {0.f, 0.f, 0.f, 0.f};
        {
            const unsigned short* hb =
                h_t + (size_t)bcol * HID + wv * 512 + kg * 8;
            #pragma unroll
            for (int kc = 0; kc < 16; ++kc) {
                const unsigned short* p = hb + kc * 32;
                union { unsigned long long u[2]; half8 h; } B;
                B.u[0] = ld_h2u(p);
                B.u[1] = ld_h2u(p + 4);
                c = __builtin_amdgcn_mfma_f32_16x16x32_f16(Af[kc], B.h, c, 0, 0, 0);
                if ((kc & 3) == 3) __builtin_amdgcn_sched_barrier(0);
            }
        }

        // ---- cross-wave K-combine: one LDS bounce + one barrier
        if (wv == 1) red[t & 1][l] = c;
        __syncthreads();
        if (wv == 0) {
            f32x4 s = c + red[t & 1][l];
            // pair a (rows 0-7, lanes<32) with z (rows 8-15, lanes>=32)
            f32x4 o;
            #pragma unroll
            for (int r = 0; r < 4; ++r) o[r] = __shfl_xor(s[r], 32);
            if (gate_lane) {
                f32x4 hnew;
                #pragma unroll
                for (int r = 0; r < 4; ++r) {
                    float at = wa4[r] + s[r];
                    float zt = wz4[r] + o[r];
                    zt = 1.f / (1.f + expf(-zt));
                    float hc = tanhf(at);
                    hnew[r] = zt * hprev[r] + (1.f - zt) * hc;
                }
                hprev = hnew;
                // output (fp16 act for layer0, fp32 out for layer1)
                if (act16) {
                    unsigned long long pk = 0;
                    #pragma unroll
                    for (int r = 0; r < 4; ++r) {
                        unsigned short us = __builtin_bit_cast(
                            unsigned short, (_Float16)hnew[r]);
                        pk |= (unsigned long long)us << (16 * r);
                    }
                    *(unsigned long long*)&act16[((size_t)bcol * TLEN + t) * HID
                                                 + jrow] = pk;
                } else {
                    *(f32x4*)&out32[((size_t)bcol * TLEN + t) * HID + jrow] = hnew;
                }
                if (t < TLEN - 1) {
                    unsigned long long pk = 0;
                    #pragma unroll
                    for (int r = 0; r < 4; ++r) {
                        unsigned short us = __builtin_bit_cast(
                            unsigned short, (_Float16)hnew[r]);
                        pk |= (unsigned long long)us << (16 * r);
                    }
                    st_h64((unsigned long long*)&h_n[(size_t)bcol * HID + jrow], pk);
                } else {
                    *(f32x4*)&hlast[(size_t)bcol * HID + jrow] = hnew;
                }
            }
            if (t < TLEN - 1) {
                asm volatile("s_waitcnt vmcnt(0)" ::: "memory");
                if (tid == 0) st_flag(&flags[wg * FSTRIDE], t + 1);
            }
        }

        unsigned short* tmp = h_t; h_t = h_n; h_n = h_p; h_p = tmp;
    }
}

// ---------------------------------------------------------------------------
extern "C" void kernel_launch(void* const* d_in, const int* in_sizes, int n_in,
                              void* d_out, int out_size, void* d_ws, size_t ws_size,
                              hipStream_t stream) {
    (void)in_sizes; (void)n_in; (void)out_size; (void)ws_size;

    const float* x  = (const float*)d_in[0];
    const float* W0 = (const float*)d_in[1];
    const float* U0 = (const float*)d_in[2];
    const float* W1 = (const float*)d_in[3];
    const float* U1 = (const float*)d_in[4];

    float* out    = (float*)d_out;                              // [B,T,H]
    float* hstack = out + (size_t)BATCH * TLEN * HID;           // [2,B,H]

    // workspace layout (all 16B-aligned)
    int*            flags = (int*)d_ws;                              // 16 KB
    unsigned short* hring = (unsigned short*)(flags + NWG * FSTRIDE);// 192 KB
    _Float16*       W16   = (_Float16*)(hring + 3 * BHID);           // 4 MB
    _Float16*       xact  = W16 + 2 * 1024 * 1024;   // 33.5 MB (x16 / act16)
    float*          wbuf  = (float*)(xact + (size_t)BATCH * TLEN * HID); // 128 MB

    dim3 gg(16384 / 128, 2048 / 128);
    int init_blocks = (BHID + 255) / 256;

    // ---- layer 0 ----
    conv_f16<<<(BATCH * TLEN * 512 / 8 + 255) / 256, 256, 0, stream>>>(
        x, xact, BATCH * TLEN * 512 / 8);
    conv_f16<<<(G2 * 512 / 8 + 255) / 256, 256, 0, stream>>>(
        W0, W16, G2 * 512 / 8);
    proj_gemm_f16<<<gg, 256, 0, stream>>>(xact, W16, wbuf, 512);
    rec_init<<<init_blocks, 256, 0, stream>>>(hring, flags);
    ligru_rec<<<dim3(NWG), dim3(128), 0, stream>>>(
        wbuf, U0, hring, flags, nullptr, xact, hstack);   // act16 out (overwrites x16 region)

    // ---- layer 1 ----
    conv_f16<<<(G2 * HID / 8 + 255) / 256, 256, 0, stream>>>(
        W1, W16, G2 * HID / 8);
    proj_gemm_f16<<<gg, 256, 0, stream>>>(xact, W16, wbuf, 1024);
    rec_init<<<init_blocks, 256, 0, stream>>>(hring, flags);
    ligru_rec<<<dim3(NWG), dim3(128), 0, stream>>>(
        wbuf, U1, hring, flags, out, nullptr, hstack + BATCH * HID);
}

// Round 12
// 4345.205 us; speedup vs baseline: 1.4726x; 1.4726x over previous
//
#include <hip/hip_runtime.h>
#include <math.h>

#define BATCH 32
#define TLEN  512
#define HID   1024
#define G2    2048   // 2*H
#define BHID (BATCH * HID)

typedef _Float16 half8 __attribute__((ext_vector_type(8)));
typedef float f32x4 __attribute__((ext_vector_type(4)));

// ---------------------------------------------------------------------------
// fp32 -> fp16 conversion (8 elems/thread)
// ---------------------------------------------------------------------------
__global__ __launch_bounds__(256)
void conv_f16(const float* __restrict__ s, _Float16* __restrict__ d, int n8) {
    int i = blockIdx.x * 256 + threadIdx.x;
    if (i < n8) {
        int base = i * 8;
        float4 v0 = *(const float4*)&s[base];
        float4 v1 = *(const float4*)&s[base + 4];
        half8 h;
        h[0] = (_Float16)v0.x; h[1] = (_Float16)v0.y;
        h[2] = (_Float16)v0.z; h[3] = (_Float16)v0.w;
        h[4] = (_Float16)v1.x; h[5] = (_Float16)v1.y;
        h[6] = (_Float16)v1.z; h[7] = (_Float16)v1.w;
        *(half8*)&d[base] = h;
    }
}

// ---------------------------------------------------------------------------
// MFMA projection GEMM (R11, proven): Cw[t][b][n] = sum_k A[m][k]*W[n][k],
// m = b*T + t. A [M,K] fp16, W [2048,K] fp16, both row-major, read straight
// from global. WG 256 thr = 4 waves (2x2), wave tile 64x64.
// ---------------------------------------------------------------------------
__global__ __launch_bounds__(256)
void proj_gemm_f16(const _Float16* __restrict__ A, const _Float16* __restrict__ W,
                   float* __restrict__ Cw, int K) {
    const int tid = threadIdx.x;
    const int wv = tid >> 6;
    const int l  = tid & 63;
    const int m0 = blockIdx.x * 128 + (wv >> 1) * 64;
    const int n0 = blockIdx.y * 128 + (wv & 1) * 64;
    const int fr = l & 15;
    const int kg = l >> 4;

    f32x4 acc[4][4];
    #pragma unroll
    for (int i = 0; i < 4; ++i)
        #pragma unroll
        for (int j = 0; j < 4; ++j) acc[i][j] = (f32x4){0.f, 0.f, 0.f, 0.f};

    const int nkc = K >> 5;
    #pragma unroll 2
    for (int kc = 0; kc < nkc; ++kc) {
        int k = kc * 32 + kg * 8;
        half8 af[4], bf[4];
        #pragma unroll
        for (int i = 0; i < 4; ++i)
            af[i] = *(const half8*)&A[(size_t)(m0 + i * 16 + fr) * K + k];
        #pragma unroll
        for (int j = 0; j < 4; ++j)
            bf[j] = *(const half8*)&W[(size_t)(n0 + j * 16 + fr) * K + k];
        #pragma unroll
        for (int i = 0; i < 4; ++i)
            #pragma unroll
            for (int j = 0; j < 4; ++j)
                acc[i][j] = __builtin_amdgcn_mfma_f32_16x16x32_f16(
                    af[i], bf[j], acc[i][j], 0, 0, 0);
    }

    // C layout: col = l&15, row = (l>>4)*4 + r
    #pragma unroll
    for (int i = 0; i < 4; ++i) {
        #pragma unroll
        for (int r = 0; r < 4; ++r) {
            int m = m0 + i * 16 + (l >> 4) * 4 + r;
            int t = m & (TLEN - 1);
            int b = m >> 9;
            float* dst = &Cw[((size_t)t * BATCH + b) * G2];
            #pragma unroll
            for (int j = 0; j < 4; ++j)
                dst[n0 + j * 16 + (l & 15)] = acc[i][j][r];
        }
    }
}

// ---------------------------------------------------------------------------
// Agent-scope (device-coherent) helpers: sc0 sc1, bypass L1/per-XCD L2.
// ---------------------------------------------------------------------------
__device__ __forceinline__ void st_flag(int* p, int v) {
    __hip_atomic_store(p, v, __ATOMIC_RELAXED, __HIP_MEMORY_SCOPE_AGENT);
}
__device__ __forceinline__ int ld_flag(const int* p) {
    return __hip_atomic_load(p, __ATOMIC_RELAXED, __HIP_MEMORY_SCOPE_AGENT);
}
__device__ __forceinline__ unsigned long long ld_h2u(const unsigned short* p) {
    return __hip_atomic_load((const unsigned long long*)p, __ATOMIC_RELAXED,
                             __HIP_MEMORY_SCOPE_AGENT);
}
__device__ __forceinline__ void st_h32(unsigned int* p, unsigned int v) {
    __hip_atomic_store(p, v, __ATOMIC_RELAXED, __HIP_MEMORY_SCOPE_AGENT);
}

#define NWG 256
#define FSTRIDE 16   // flags 64 B apart
#define BT 8         // batches per WG
#define JT 16        // a-rows per WG (plus JT z-rows)

__global__ void rec_init(unsigned short* h0, int* flags) {
    int i = blockIdx.x * 256 + threadIdx.x;
    if (i < BHID) h0[i] = 0;              // fp16 +0.0
    if (i < NWG * FSTRIDE) flags[i] = 0;
}

// ---------------------------------------------------------------------------
// MFMA recurrence = R10 skeleton (512 thr / 8 waves, 4 sync groups x 64 WGs,
// 3-ring, coherent B-frags, A-frags in reg) with the publish barrier removed:
// gates are confined to WAVE 0 (64 lanes x 2 outputs), so publish is
// wave-0-local (vmcnt(0) + flag store). 2 barriers/step instead of 3.
// red single-buffer is safe: waves 1-7 write red(t+1) only after the
// post-poll barrier of t+1, which wave 0 joins only after consuming red(t).
// ---------------------------------------------------------------------------
__global__ __launch_bounds__(512, 1)
void ligru_rec(const float* __restrict__ w,        // [T][B][2H] fp32
               const float* __restrict__ U,        // [2H][H] fp32
               unsigned short* __restrict__ hring, // [3][B][H] fp16 ring
               int* __restrict__ flags,            // NWG*FSTRIDE, pre-zeroed
               float* __restrict__ out32,          // [B][T][H] fp32 (layer 1)
               _Float16* __restrict__ act16,       // [B][T][H] fp16 (layer 0)
               float* __restrict__ hlast) {        // [B][H] fp32
    __shared__ float red[8][32][17];               // wave C partials (17 KB)

    const int wg  = blockIdx.x;
    const int tid = threadIdx.x;
    const int bt  = wg & 3;
    const int jb  = wg >> 2;          // 0..63
    const int j0  = jb * JT;
    const int bg0 = bt * BT;

    const int wv   = tid >> 6;        // wave 0..7: K-chunks wv*4..wv*4+3
    const int l    = tid & 63;
    const int mrow = l & 15;          // A-frag M row
    const int kg   = l >> 4;          // k-group (8 halves)
    const int bcol = bg0 + (l & 7);   // B-frag batch (cols 8-15 duplicate)

    // ---- A frags: U fp32 -> fp16 once (8 frags = 32 VGPRs, static)
    half8 Aa[4], Az[4];
    #pragma unroll
    for (int kc = 0; kc < 4; ++kc) {
        int k0 = (wv * 4 + kc) * 32 + kg * 8;
        const float* pa = &U[(size_t)(j0 + mrow) * HID + k0];
        const float* pz = &U[(size_t)(HID + j0 + mrow) * HID + k0];
        float4 a0 = *(const float4*)pa, a1 = *(const float4*)(pa + 4);
        float4 z0 = *(const float4*)pz, z1 = *(const float4*)(pz + 4);
        half8 va, vz;
        va[0] = (_Float16)a0.x; va[1] = (_Float16)a0.y;
        va[2] = (_Float16)a0.z; va[3] = (_Float16)a0.w;
        va[4] = (_Float16)a1.x; va[5] = (_Float16)a1.y;
        va[6] = (_Float16)a1.z; va[7] = (_Float16)a1.w;
        vz[0] = (_Float16)z0.x; vz[1] = (_Float16)z0.y;
        vz[2] = (_Float16)z0.z; vz[3] = (_Float16)z0.w;
        vz[4] = (_Float16)z1.x; vz[5] = (_Float16)z1.y;
        vz[6] = (_Float16)z1.z; vz[7] = (_Float16)z1.w;
        Aa[kc] = va; Az[kc] = vz;
    }

    unsigned short* h_t = hring;
    unsigned short* h_n = hring + BHID;
    unsigned short* h_p = hring + 2 * BHID;

    // gate coords (wave 0 only): lane l -> j-pair (gjl, gjl+1) x batch gbl
    const int gjl = (l & 7) * 2;      // 0,2,..,14
    const int gbl = l >> 3;           // 0..7
    const int gbg = bg0 + gbl;
    float hp0 = 0.f, hp1 = 0.f;       // private h state (2 outputs/lane)

    for (int t = 0; t < TLEN; ++t) {
        // ---- wave 0: w prefetch (issued before poll; hides under spin)
        float2 wa2 = {0.f, 0.f}, wz2 = {0.f, 0.f};
        if (wv == 0) {
            const float* wt = &w[((size_t)t * BATCH + gbg) * G2];
            wa2 = *(const float2*)&wt[j0 + gjl];
            wz2 = *(const float2*)&wt[HID + j0 + gjl];
            // ---- poll the 64 group flags (1 per lane, 16K pollers total)
            if (t > 0) {
                const int* fp = &flags[(bt + (l << 2)) * FSTRIDE];
                while (ld_flag(fp) < t)
                    __builtin_amdgcn_s_sleep(1);
            }
        }
        __syncthreads();   // barrier A: h(t) visible to all waves

        // ---- B frags from coherent ring + MFMA (8 per wave)
        f32x4 ca = {0.f, 0.f, 0.f, 0.f};
        f32x4 cz = {0.f, 0.f, 0.f, 0.f};
        #pragma unroll
        for (int kc = 0; kc < 4; ++kc) {
            int k0 = (wv * 4 + kc) * 32 + kg * 8;
            const unsigned short* hp = &h_t[(size_t)bcol * HID + k0];
            union { unsigned long long u[2]; half8 h; } B;
            B.u[0] = ld_h2u(hp);
            B.u[1] = ld_h2u(hp + 4);
            ca = __builtin_amdgcn_mfma_f32_16x16x32_f16(Aa[kc], B.h, ca, 0, 0, 0);
            cz = __builtin_amdgcn_mfma_f32_16x16x32_f16(Az[kc], B.h, cz, 0, 0, 0);
        }

        // ---- C layout: col = l&15 (batch), row = (l>>4)*4 + r (j)
        #pragma unroll
        for (int r = 0; r < 4; ++r) {
            red[wv][kg * 4 + r][l & 15]      = ca[r];
            red[wv][16 + kg * 4 + r][l & 15] = cz[r];
        }
        __syncthreads();   // barrier B: partials complete

        // ---- wave 0: reduce + gates + publish (no block barrier)
        if (wv == 0) {
            float sa0 = 0.f, sa1 = 0.f, sz0 = 0.f, sz1 = 0.f;
            #pragma unroll
            for (int v = 0; v < 8; ++v) {
                sa0 += red[v][gjl][gbl];
                sa1 += red[v][gjl + 1][gbl];
                sz0 += red[v][16 + gjl][gbl];
                sz1 += red[v][16 + gjl + 1][gbl];
            }
            float at0 = wa2.x + sa0, at1 = wa2.y + sa1;
            float zt0 = wz2.x + sz0, zt1 = wz2.y + sz1;
            zt0 = 1.f / (1.f + expf(-zt0));
            zt1 = 1.f / (1.f + expf(-zt1));
            float hc0 = tanhf(at0), hc1 = tanhf(at1);
            float hn0 = zt0 * hp0 + (1.f - zt0) * hc0;
            float hn1 = zt1 * hp1 + (1.f - zt1) * hc1;
            hp0 = hn0; hp1 = hn1;

            size_t oidx = ((size_t)gbg * TLEN + t) * HID + j0 + gjl;
            unsigned short u0 = __builtin_bit_cast(unsigned short, (_Float16)hn0);
            unsigned short u1 = __builtin_bit_cast(unsigned short, (_Float16)hn1);
            unsigned int pk = (unsigned int)u0 | ((unsigned int)u1 << 16);
            if (act16) {
                *(unsigned int*)&act16[oidx] = pk;
            } else {
                *(float2*)&out32[oidx] = make_float2(hn0, hn1);
            }
            if (t < TLEN - 1) {
                st_h32((unsigned int*)&h_n[(size_t)gbg * HID + j0 + gjl], pk);
                asm volatile("s_waitcnt vmcnt(0)" ::: "memory");
                if (l == 0) st_flag(&flags[wg * FSTRIDE], t + 1);
            } else {
                *(float2*)&hlast[(size_t)gbg * HID + j0 + gjl] =
                    make_float2(hn0, hn1);
            }
        }

        unsigned short* tmp = h_t; h_t = h_n; h_n = h_p; h_p = tmp;
    }
}

// ---------------------------------------------------------------------------
extern "C" void kernel_launch(void* const* d_in, const int* in_sizes, int n_in,
                              void* d_out, int out_size, void* d_ws, size_t ws_size,
                              hipStream_t stream) {
    (void)in_sizes; (void)n_in; (void)out_size; (void)ws_size;

    const float* x  = (const float*)d_in[0];
    const float* W0 = (const float*)d_in[1];
    const float* U0 = (const float*)d_in[2];
    const float* W1 = (const float*)d_in[3];
    const float* U1 = (const float*)d_in[4];

    float* out    = (float*)d_out;                              // [B,T,H]
    float* hstack = out + (size_t)BATCH * TLEN * HID;           // [2,B,H]

    // workspace layout (all 16B-aligned)
    int*            flags = (int*)d_ws;                              // 16 KB
    unsigned short* hring = (unsigned short*)(flags + NWG * FSTRIDE);// 192 KB
    _Float16*       W16   = (_Float16*)(hring + 3 * BHID);           // 4 MB
    _Float16*       xact  = W16 + 2 * 1024 * 1024;   // 33.5 MB (x16 / act16)
    float*          wbuf  = (float*)(xact + (size_t)BATCH * TLEN * HID); // 128 MB

    dim3 gg(16384 / 128, 2048 / 128);
    int init_blocks = (BHID + 255) / 256;

    // ---- layer 0 ----
    conv_f16<<<(BATCH * TLEN * 512 / 8 + 255) / 256, 256, 0, stream>>>(
        x, xact, BATCH * TLEN * 512 / 8);
    conv_f16<<<(G2 * 512 / 8 + 255) / 256, 256, 0, stream>>>(
        W0, W16, G2 * 512 / 8);
    proj_gemm_f16<<<gg, 256, 0, stream>>>(xact, W16, wbuf, 512);
    rec_init<<<init_blocks, 256, 0, stream>>>(hring, flags);
    ligru_rec<<<dim3(NWG), dim3(512), 0, stream>>>(
        wbuf, U0, hring, flags, nullptr, xact, hstack);  // fp16 act out

    // ---- layer 1 ----
    conv_f16<<<(G2 * HID / 8 + 255) / 256, 256, 0, stream>>>(
        W1, W16, G2 * HID / 8);
    proj_gemm_f16<<<gg, 256, 0, stream>>>(xact, W16, wbuf, 1024);
    rec_init<<<init_blocks, 256, 0, stream>>>(hring, flags);
    ligru_rec<<<dim3(NWG), dim3(512), 0, stream>>>(
        wbuf, U1, hring, flags, out, nullptr, hstack + BATCH * HID);
}